// Round 9
// baseline (202.205 us; speedup 1.0000x reference)
//
#include <hip/hip_runtime.h>
#include <hip/hip_bf16.h>
#include <math.h>

typedef __bf16 bf16;
typedef __bf16 bf16x8 __attribute__((ext_vector_type(8)));
typedef __bf16 bf16x4 __attribute__((ext_vector_type(4)));
typedef float f32x4 __attribute__((ext_vector_type(4)));
typedef short s16x4 __attribute__((ext_vector_type(4)));

#define MFMA16(a, b, c) __builtin_amdgcn_mfma_f32_16x16x32_bf16((a), (b), (c), 0, 0, 0)
// K=16 bf16 MFMA: B-frag layout B[k=g*4+j][col=c15] matches QK^T C-layout directly.
#define MFMA16K16(a, b, c) __builtin_amdgcn_mfma_f32_16x16x16bf16_1k((a), (b), (c), 0, 0, 0)
#define EXP2F(x) __builtin_amdgcn_exp2f(x)  // v_exp_f32: computes 2^x

// async global->LDS, 16B per lane; LDS dest = (wave-uniform) base + lane*16
__device__ __forceinline__ void gl_lds16(const bf16* g, bf16* l) {
  __builtin_amdgcn_global_load_lds(
      (const __attribute__((address_space(1))) void*)g,
      (__attribute__((address_space(3))) void*)l, 16, 0, 0);
}

// problem dims
static constexpr int B_N = 2, S_N = 2048, DM = 1024, H_N = 16, DK = 64;
static constexpr int M_N = B_N * S_N;             // 4096
static constexpr size_t NX = (size_t)M_N * DM;    // 4M elements
static constexpr size_t NW = (size_t)DM * DM;     // 1M elements
// workspace layout (bf16 elements)
static constexpr size_t OFF_X = 0;
static constexpr size_t OFF_W = NX;               // Wq,Wk,Wv,Wo
static constexpr size_t OFF_Q = OFF_W + 4 * NW;   // Q [b,h,s,d] (pre-scaled by log2e/8, roped)
static constexpr size_t OFF_K = OFF_Q + NX;       // K [b,h,s,d] (roped)
static constexpr size_t OFF_V = OFF_K + NX;       // V^T [b,h,d,s] (key order interleaved per 32)
static constexpr size_t OFF_C = OFF_V + NX;       // ctx [b,s,h*d]; rope table aliases its head
// total 24M bf16 = 48 MB

// ---------------- fp32 -> bf16 cast + RoPE table (fused) ----------------
__global__ __launch_bounds__(256) void cast_all(
    const float* __restrict__ x, const float* __restrict__ wq,
    const float* __restrict__ wk, const float* __restrict__ wv,
    const float* __restrict__ wo, bf16* __restrict__ dst,
    float2* __restrict__ tab) {
  size_t i = ((size_t)blockIdx.x * 256 + threadIdx.x) * 4;
  const float* src;
  size_t off;
  if (i < NX) {
    src = x; off = i;
  } else {
    size_t e = i - NX;
    int wi = (int)(e >> 20);
    src = (wi == 0) ? wq : (wi == 1) ? wk : (wi == 2) ? wv : wo;
    off = e & (NW - 1);
  }
  float4 v = *(const float4*)(src + off);
  bf16x4 o = {(bf16)v.x, (bf16)v.y, (bf16)v.z, (bf16)v.w};
  *(bf16x4*)(dst + i) = o;
  if (blockIdx.x < 256) {
    int t = blockIdx.x * 256 + threadIdx.x;  // 65536 entries
    int s = t >> 5, j = t & 31;
    float invf = powf(10000.f, -(float)(2 * j) / 64.f);
    float sn, cs;
    sincosf((float)s * invf, &sn, &cs);
    tab[t] = make_float2(cs, sn);
  }
}

// ---------------- QKV GEMM (M=4096,N=3072,K=1024) + fused RoPE, V written transposed ----------------
// R19: BK=32 double-buffer, ONE barrier/step (stage kt+1 during compute of kt).
// R17's dbuf regressed because the 3.15M bank conflicts were still present (LDS port
// saturated); R18 fixed conflicts via both-sides granule-XOR. Now add the prefetch:
// same 32KB LDS (5 blocks/CU), same 32-barrier count as R18, loads hidden under compute.
// 4-slot swizzle: LDS slot s of row r holds source granule s ^ (r&3) ^ ((r>>2)&3);
// per g-group the (bank-half, slot) pairs occur exactly 2x -> 2 lanes/bank = free (m136).
__global__ __launch_bounds__(256) void gemm_qkv_rope(
    const bf16* __restrict__ X, const bf16* __restrict__ W3,
    const int* __restrict__ pos_ids, const float2* __restrict__ tab,
    bf16* __restrict__ Qo, bf16* __restrict__ Ko, bf16* __restrict__ Vt) {
  __shared__ __align__(16) bf16 As[2][128 * 32];
  __shared__ __align__(16) bf16 Bs[2][128 * 32];
  const int tid = threadIdx.x;
  const int wave = tid >> 6, lane = tid & 63;
  const int c15 = lane & 15, g = lane >> 4;
  const int fc = (c15 & 3) ^ ((c15 >> 2) & 3);  // read-side swizzle key
  const int mw = (wave & 1) * 64, nw = (wave >> 1) * 64;
  const int row0 = blockIdx.x * 128;
  const int n0 = blockIdx.y * 128;
  const bf16* Asrc = X + (size_t)row0 * DM;
  const bf16* Bsrc = W3 + (size_t)n0 * DM;

  // staging: 128 rows x 4 slots = 512 granules per matrix; 2/thread.
  // source col granule = slot ^ (r&3) ^ ((r>>2)&3)  (swizzle on the global side).
#define QKV_STAGE(kt_, b_)                                                     \
  _Pragma("unroll") for (int j = 0; j < 2; ++j) {                              \
    const int id = j * 256 + tid;                                              \
    const int rr = id >> 2, sp = id & 3;                                       \
    const int cs = sp ^ (rr & 3) ^ ((rr >> 2) & 3);                            \
    gl_lds16(Asrc + (size_t)rr * DM + (kt_)*32 + cs * 8,                       \
             &As[b_][j * 2048 + wave * 512 + lane * 8]);                       \
    gl_lds16(Bsrc + (size_t)rr * DM + (kt_)*32 + cs * 8,                       \
             &Bs[b_][j * 2048 + wave * 512 + lane * 8]);                       \
  }

  f32x4 acc[4][4] = {};
  QKV_STAGE(0, 0)
  for (int kt = 0; kt < DM / 32; ++kt) {
    const int b = kt & 1;
    __syncthreads();  // per-wave vmcnt drain at barrier -> tile kt resident; WAR for b^1
    if (kt + 1 < DM / 32) QKV_STAGE(kt + 1, b ^ 1)
    bf16x8 af[4], bfr[4];
#pragma unroll
    for (int t = 0; t < 4; ++t) {
      const int slot = g ^ fc;
      af[t] = *(const bf16x8*)&As[b][(mw + t * 16 + c15) * 32 + slot * 8];
      bfr[t] = *(const bf16x8*)&Bs[b][(nw + t * 16 + c15) * 32 + slot * 8];
    }
#pragma unroll
    for (int mt = 0; mt < 4; ++mt)
#pragma unroll
      for (int nt = 0; nt < 4; ++nt)
        acc[mt][nt] = MFMA16(af[mt], bfr[nt], acc[mt][nt]);
  }
#undef QKV_STAGE

  // epilogue: C/D col = nt*16+c15, row = g*4+r
  const int Wsel = n0 >> 10;             // 0=q, 1=k, 2=v
  const int colbase = (n0 & 1023) + nw;  // multiple of 64 -> one head
  const int h = colbase >> 6;
  if (Wsel == 2) {
#pragma unroll
    for (int mt = 0; mt < 4; ++mt) {
      const int srow = row0 + mw + mt * 16 + g * 4;
      const int bb = srow >> 11, ss = srow & 2047;
      // interleave key order within each 32-block so flash's PV K=16 chunk pair
      // (keys {4g..4g+3, 16+4g..16+4g+3}) is one contiguous b128 granule:
      // p = (k&~31) | ((k&12)<<1) | ((k&16)>>2) | (k&3); ss is a multiple of 4.
      const int ssp = (ss & ~31) | ((ss & 12) << 1) | ((ss & 16) >> 2);
      const size_t vb = ((size_t)(bb * H_N + h) * DK) * S_N + ssp;
#pragma unroll
      for (int nt = 0; nt < 4; ++nt) {
        bf16x4 v4;
#pragma unroll
        for (int r = 0; r < 4; ++r) v4[r] = (bf16)acc[mt][nt][r];
        *(bf16x4*)&Vt[vb + (size_t)(nt * 16 + c15) * S_N] = v4;
      }
    }
  } else {
    bf16* dst = (Wsel == 0) ? Qo : Ko;
    // Q pre-scale folds 1/sqrt(64) AND log2(e) so flash can use exp2 directly.
    const float sc = (Wsel == 0) ? 0.125f * 1.44269504088896f : 1.0f;
#pragma unroll
    for (int mt = 0; mt < 4; ++mt) {
#pragma unroll
      for (int r = 0; r < 4; ++r) {
        const int row = row0 + mw + mt * 16 + g * 4 + r;
        const int bb = row >> 11, ss = row & 2047;
        const int pos = pos_ids[row];
        const float2 c0 = tab[pos * 32 + c15];       // freq j = c15
        const float2 c1 = tab[pos * 32 + 16 + c15];  // freq j = 16+c15
        const size_t base = ((size_t)(bb * H_N + h) * S_N + ss) * DK;
#pragma unroll
        for (int ntp = 0; ntp < 2; ++ntp) {
          float x1 = acc[mt][ntp][r], x2 = acc[mt][ntp + 2][r];
          float cs = ntp ? c1.x : c0.x, sn = ntp ? c1.y : c0.y;
          dst[base + ntp * 16 + c15] = (bf16)((x1 * cs - x2 * sn) * sc);
          dst[base + ntp * 16 + c15 + 32] = (bf16)((x2 * cs + x1 * sn) * sc);
        }
      }
    }
  }
}

// ---------------- flash attention: 8 waves = (qh: 4 x 32-q) x (ky: 2 x 32-key slice) ----------------
// R14 structure (best verified: 53.4us, MfmaUtil 39, VALU 46, conflicts 65K). R15/R16
// alternatives (re-shard, barrier-free) both regressed; with 85% combined pipe util this
// mix is near its structural floor. PV uses K=16 MFMA whose B-frag layout IS the QK^T
// C-layout register pair; V A-frags come from ONE b128 read (producer-side interleave).
__global__ __launch_bounds__(512, 2) void flash_attn(
    const bf16* __restrict__ Q, const bf16* __restrict__ K,
    const bf16* __restrict__ Vt, bf16* __restrict__ ctx) {
  // staging: K[ky][buf] at (ky*2+buf)*2048, V at 8192+...; merge redbuf aliases smem
  // (needs 4 qh x 32 rows x 68 floats = 34816 B = 17408 elements -> smem sized for merge).
  __shared__ __align__(16) bf16 smem[17408];
  __shared__ float lred[4][2][16];
  float* redbuf = (float*)smem;

  const int tid = threadIdx.x;
  const int wave = tid >> 6, lane = tid & 63;
  const int c15 = lane & 15, g = lane >> 4;
  const int qh = wave >> 1, ky = wave & 1;  // qh 0..3 (32-q slice), ky 0..1 (32-key slice)
  const int bh = blockIdx.x & 31;   // b*16+h (XCD = bh%8)
  const int qt = blockIdx.x >> 5;   // 128-query tile, 0..15
  const size_t hb = (size_t)bh * S_N * DK;
  const bf16* Qb = Q + hb;
  const bf16* Kb = K + hb;
  const bf16* Vb = Vt + hb;  // [d][s] rows, stride S_N (keys interleaved per 32)

  // Q B-frags: 2 q-tiles of 16 for this wave's 32-query slice
  const int qb = qt * 128 + qh * 32;
  bf16x8 qf[2][2];
#pragma unroll
  for (int t = 0; t < 2; ++t) {
    qf[t][0] = *(const bf16x8*)&Qb[(size_t)(qb + t * 16 + c15) * DK + g * 8];
    qf[t][1] = *(const bf16x8*)&Qb[(size_t)(qb + t * 16 + c15) * DK + 32 + g * 8];
  }

  f32x4 O[2][4] = {};  // [q-tile][d-tile]: O^T row d = nt*16+g*4+r, col q = c15
  float l[2] = {0.f, 0.f};
  const int sw = c15 & 7;
  const int vslot = (g + (c15 >> 1)) & 3;  // V read-granule swizzle

  constexpr int NTK = S_N / 64;  // 32 iters; each wave sees its ky 32-key slice
#define STAGE(kt_, b_)                                                            \
  if (qh == 0) { /* stage K slice ky */                                           \
    const bf16* Ksrc = Kb + (size_t)((kt_)*64 + ky * 32) * DK;                    \
    _Pragma("unroll") for (int c = 0; c < 4; ++c) {                               \
      const int gi = c * 64 + lane;                                               \
      const int rr = gi >> 3, cp = gi & 7;                                        \
      const int cd = cp ^ (rr & 7);                                               \
      gl_lds16(Ksrc + (size_t)rr * 64 + cd * 8, &smem[(ky * 2 + (b_)) * 2048 + c * 512]); \
    }                                                                             \
  } else if (qh == 1) { /* stage V slice ky */                                    \
    const bf16* Vsrc = Vb + (kt_)*64 + ky * 32;                                   \
    _Pragma("unroll") for (int c = 0; c < 4; ++c) {                               \
      const int gi = c * 64 + lane;                                               \
      const int rv = gi >> 2, cpv = gi & 3;                                       \
      const int cdv = (cpv - ((rv & 15) >> 1)) & 3;                               \
      gl_lds16(Vsrc + (size_t)rv * S_N + cdv * 8, &smem[8192 + (ky * 2 + (b_)) * 2048 + c * 512]); \
    }                                                                             \
  }

  STAGE(0, 0)
  for (int kt = 0; kt < NTK; ++kt) {
    __syncthreads();  // tile kt resident (its loads were issued one full phase ago)
    if (kt + 1 < NTK) STAGE(kt + 1, (kt + 1) & 1)
    const bf16* Kl = &smem[(ky * 2 + (kt & 1)) * 2048];
    const bf16* Vl = &smem[8192 + (ky * 2 + (kt & 1)) * 2048];

    // K A-frags: 2 key-subtiles x 2 d-halves (granule-XOR swizzle, round-trips cd)
    bf16x8 kf[2][2];
#pragma unroll
    for (int nt = 0; nt < 2; ++nt) {
      const int krow = (nt * 16 + c15) * 64;
      kf[nt][0] = *(const bf16x8*)&Kl[krow + ((g ^ sw) * 8)];
      kf[nt][1] = *(const bf16x8*)&Kl[krow + (((4 | g) ^ sw) * 8)];
    }
    // V A-frags: 4 d-subtiles; granule g holds keys {4g..4g+3, 16+4g..16+4g+3}
    // (producer-side interleave) = the two K=16 A-frags, lo/hi half of one b128.
    union VF { bf16x8 v8; s16x4 half_[2]; } vf[4];
#pragma unroll
    for (int nt = 0; nt < 4; ++nt)
      vf[nt].v8 = *(const bf16x8*)&Vl[(nt * 16 + c15) * 32 + vslot * 8];

    // per q-tile: S^T = K·Q^T (32 keys x 16 q) -> exp2 -> PV via 2x K=16 MFMA (no P movement)
#pragma unroll
    for (int t = 0; t < 2; ++t) {
      f32x4 s0 = {}, s1 = {};
      s0 = MFMA16(kf[0][0], qf[t][0], s0);
      s0 = MFMA16(kf[0][1], qf[t][1], s0);
      s1 = MFMA16(kf[1][0], qf[t][0], s1);
      s1 = MFMA16(kf[1][1], qf[t][1], s1);
      union PK { s16x4 s4; bf16 h[4]; };
      PK A, Bp;
      float p0 = EXP2F(s0[0]), p1 = EXP2F(s0[1]), p2 = EXP2F(s0[2]), p3 = EXP2F(s0[3]);
      float p4 = EXP2F(s1[0]), p5 = EXP2F(s1[1]), p6 = EXP2F(s1[2]), p7 = EXP2F(s1[3]);
      l[t] += ((p0 + p1) + (p2 + p3)) + ((p4 + p5) + (p6 + p7));
      A.h[0] = (bf16)p0; A.h[1] = (bf16)p1; A.h[2] = (bf16)p2; A.h[3] = (bf16)p3;
      Bp.h[0] = (bf16)p4; Bp.h[1] = (bf16)p5; Bp.h[2] = (bf16)p6; Bp.h[3] = (bf16)p7;
      // A = P[keys 4g..4g+3][q=c15] = K=16 B-frag chunk0; Bp = keys 16+4g..+3 = chunk1.
#pragma unroll
      for (int nt = 0; nt < 4; ++nt) {
        O[t][nt] = MFMA16K16(vf[nt].half_[0], A.s4, O[t][nt]);
        O[t][nt] = MFMA16K16(vf[nt].half_[1], Bp.s4, O[t][nt]);
      }
    }
  }
#undef STAGE

  // own-wave l reduction (sum over g-lanes sharing c15)
#pragma unroll
  for (int t = 0; t < 2; ++t) {
    l[t] += __shfl_xor(l[t], 16);
    l[t] += __shfl_xor(l[t], 32);
  }

  // cross-wave merge: ky=1 publishes O,l; ky=0 combines, normalizes, stores.
  __syncthreads();  // all waves done reading staging LDS (redbuf aliases it)
  if (ky == 1) {
#pragma unroll
    for (int t = 0; t < 2; ++t) {
#pragma unroll
      for (int nt = 0; nt < 4; ++nt)
        *(f32x4*)&redbuf[(qh * 32 + t * 16 + c15) * 68 + nt * 16 + g * 4] = O[t][nt];
      if (g == 0) lred[qh][t][c15] = l[t];
    }
  }
  __syncthreads();
  if (ky == 0) {
    const int bb = bh >> 4, hh = bh & 15;
#pragma unroll
    for (int t = 0; t < 2; ++t) {
      const float inv = 1.0f / (l[t] + lred[qh][t][c15]);
      const size_t base = ((size_t)(bb * S_N + qb + t * 16 + c15) * H_N + hh) * DK;
#pragma unroll
      for (int nt = 0; nt < 4; ++nt) {
        f32x4 o = *(const f32x4*)&redbuf[(qh * 32 + t * 16 + c15) * 68 + nt * 16 + g * 4];
        bf16x4 v4;
#pragma unroll
        for (int r = 0; r < 4; ++r) v4[r] = (bf16)((O[t][nt][r] + o[r]) * inv);
        *(bf16x4*)&ctx[base + nt * 16 + g * 4] = v4;
      }
    }
  }
}

// ---------------- output projection: out = ctx @ Wo^T (fp32), 64x128 tiles ----------------
// R19: same BK=32 dbuf + 4-slot swizzle as gemm_qkv.
__global__ __launch_bounds__(256) void gemm_out(
    const bf16* __restrict__ Cx, const bf16* __restrict__ Wo,
    float* __restrict__ out) {
  __shared__ __align__(16) bf16 As[2][64 * 32];
  __shared__ __align__(16) bf16 Bs[2][128 * 32];
  const int tid = threadIdx.x;
  const int wave = tid >> 6, lane = tid & 63;
  const int c15 = lane & 15, g = lane >> 4;
  const int fc = (c15 & 3) ^ ((c15 >> 2) & 3);
  const int mw = (wave & 1) * 32, nw = (wave >> 1) * 64;
  const int row0 = blockIdx.x * 64;
  const int n0 = blockIdx.y * 128;
  const bf16* Asrc = Cx + (size_t)row0 * DM;
  const bf16* Bsrc = Wo + (size_t)n0 * DM;

#define OUT_STAGE(kt_, b_)                                                     \
  {                                                                            \
    const int rA = tid >> 2, spA = tid & 3;                                    \
    const int csA = spA ^ (rA & 3) ^ ((rA >> 2) & 3);                          \
    gl_lds16(Asrc + (size_t)rA * DM + (kt_)*32 + csA * 8,                      \
             &As[b_][wave * 512 + lane * 8]);                                  \
    _Pragma("unroll") for (int j = 0; j < 2; ++j) {                            \
      const int id = j * 256 + tid;                                            \
      const int rr = id >> 2, sp = id & 3;                                     \
      const int cs = sp ^ (rr & 3) ^ ((rr >> 2) & 3);                          \
      gl_lds16(Bsrc + (size_t)rr * DM + (kt_)*32 + cs * 8,                     \
               &Bs[b_][j * 2048 + wave * 512 + lane * 8]);                     \
    }                                                                          \
  }

  f32x4 acc[2][4] = {};
  OUT_STAGE(0, 0)
  for (int kt = 0; kt < DM / 32; ++kt) {
    const int b = kt & 1;
    __syncthreads();  // tile kt resident; WAR for b^1
    if (kt + 1 < DM / 32) OUT_STAGE(kt + 1, b ^ 1)
    const int slot = g ^ fc;
    bf16x8 af[2], bfr[4];
#pragma unroll
    for (int t = 0; t < 2; ++t)
      af[t] = *(const bf16x8*)&As[b][(mw + t * 16 + c15) * 32 + slot * 8];
#pragma unroll
    for (int t = 0; t < 4; ++t)
      bfr[t] = *(const bf16x8*)&Bs[b][(nw + t * 16 + c15) * 32 + slot * 8];
#pragma unroll
    for (int mt = 0; mt < 2; ++mt)
#pragma unroll
      for (int nt = 0; nt < 4; ++nt)
        acc[mt][nt] = MFMA16(af[mt], bfr[nt], acc[mt][nt]);
  }
#undef OUT_STAGE
#pragma unroll
  for (int mt = 0; mt < 2; ++mt)
#pragma unroll
    for (int r = 0; r < 4; ++r) {
      const int row = row0 + mw + mt * 16 + g * 4 + r;
#pragma unroll
      for (int nt = 0; nt < 4; ++nt)
        out[(size_t)row * DM + n0 + nw + nt * 16 + c15] = acc[mt][nt][r];
    }
}

extern "C" void kernel_launch(void* const* d_in, const int* in_sizes, int n_in,
                              void* d_out, int out_size, void* d_ws, size_t ws_size,
                              hipStream_t stream) {
  const float* hs = (const float*)d_in[0];
  const int* pos = (const int*)d_in[1];
  const float* wq = (const float*)d_in[2];
  const float* wk = (const float*)d_in[3];
  const float* wv = (const float*)d_in[4];
  const float* wo = (const float*)d_in[5];
  float* out = (float*)d_out;
  bf16* ws = (bf16*)d_ws;
  float2* tab = (float2*)(ws + OFF_C);  // aliases ctx region; disjoint lifetime

  cast_all<<<8192, 256, 0, stream>>>(hs, wq, wk, wv, wo, ws, tab);

  dim3 gq(M_N / 128, (3 * DM) / 128);
  gemm_qkv_rope<<<gq, 256, 0, stream>>>(ws + OFF_X, ws + OFF_W, pos, tab,
                                        ws + OFF_Q, ws + OFF_K, ws + OFF_V);

  // grid 512: blockIdx = qt*32 + bh (128-query tiles, XCD-local per head); 512 threads = 8 waves
  flash_attn<<<B_N * H_N * (S_N / 128), 512, 0, stream>>>(
      ws + OFF_Q, ws + OFF_K, ws + OFF_V, ws + OFF_C);

  dim3 go(M_N / 64, DM / 128);
  gemm_out<<<go, 256, 0, stream>>>(ws + OFF_C, ws + OFF_W + 3 * NW, out);
}

// Round 10
// 179.401 us; speedup vs baseline: 1.1271x; 1.1271x over previous
//
#include <hip/hip_runtime.h>
#include <hip/hip_bf16.h>
#include <math.h>

typedef __bf16 bf16;
typedef __bf16 bf16x8 __attribute__((ext_vector_type(8)));
typedef __bf16 bf16x4 __attribute__((ext_vector_type(4)));
typedef float f32x4 __attribute__((ext_vector_type(4)));
typedef short s16x4 __attribute__((ext_vector_type(4)));

#define MFMA16(a, b, c) __builtin_amdgcn_mfma_f32_16x16x32_bf16((a), (b), (c), 0, 0, 0)
#define EXP2F(x) __builtin_amdgcn_exp2f(x)  // v_exp_f32: computes 2^x

// async global->LDS, 16B per lane; LDS dest = (wave-uniform) base + lane*16
__device__ __forceinline__ void gl_lds16(const bf16* g, bf16* l) {
  __builtin_amdgcn_global_load_lds(
      (const __attribute__((address_space(1))) void*)g,
      (__attribute__((address_space(3))) void*)l, 16, 0, 0);
}

// problem dims
static constexpr int B_N = 2, S_N = 2048, DM = 1024, H_N = 16, DK = 64;
static constexpr int M_N = B_N * S_N;             // 4096
static constexpr size_t NX = (size_t)M_N * DM;    // 4M elements
static constexpr size_t NW = (size_t)DM * DM;     // 1M elements
// workspace layout (bf16 elements)
static constexpr size_t OFF_X = 0;
static constexpr size_t OFF_W = NX;               // Wq,Wk,Wv,Wo
static constexpr size_t OFF_Q = OFF_W + 4 * NW;   // Q [b,h,s,d] (pre-scaled by log2e/8, roped)
static constexpr size_t OFF_K = OFF_Q + NX;       // K [b,h,s,d] (roped)
static constexpr size_t OFF_V = OFF_K + NX;       // V^T [b,h,d,s] (key order interleaved per 32)
static constexpr size_t OFF_C = OFF_V + NX;       // ctx [b,s,h*d]; rope table aliases its head
// total 24M bf16 = 48 MB

// ---------------- fp32 -> bf16 cast + RoPE table (fused) ----------------
__global__ __launch_bounds__(256) void cast_all(
    const float* __restrict__ x, const float* __restrict__ wq,
    const float* __restrict__ wk, const float* __restrict__ wv,
    const float* __restrict__ wo, bf16* __restrict__ dst,
    float2* __restrict__ tab) {
  size_t i = ((size_t)blockIdx.x * 256 + threadIdx.x) * 4;
  const float* src;
  size_t off;
  if (i < NX) {
    src = x; off = i;
  } else {
    size_t e = i - NX;
    int wi = (int)(e >> 20);
    src = (wi == 0) ? wq : (wi == 1) ? wk : (wi == 2) ? wv : wo;
    off = e & (NW - 1);
  }
  float4 v = *(const float4*)(src + off);
  bf16x4 o = {(bf16)v.x, (bf16)v.y, (bf16)v.z, (bf16)v.w};
  *(bf16x4*)(dst + i) = o;
  if (blockIdx.x < 256) {
    int t = blockIdx.x * 256 + threadIdx.x;  // 65536 entries
    int s = t >> 5, j = t & 31;
    float invf = powf(10000.f, -(float)(2 * j) / 64.f);
    float sn, cs;
    sincosf((float)s * invf, &sn, &cs);
    tab[t] = make_float2(cs, sn);
  }
}

// ---------------- QKV GEMM (M=4096,N=3072,K=1024) + fused RoPE, V written transposed ----------------
// R18 structure (best verified, total 189.7): BK=64 single-buffer, 16 K-steps,
// both-sides granule-XOR swizzle (LDS slot s of row r holds source granule s^(r&7);
// staging pre-swizzles the GLOBAL source col, linear gl_lds dest - m173 rule).
// R17/R19 dbuf variants both regressed (57-58us, conflicts 3.1M) - do not revisit.
__global__ __launch_bounds__(256) void gemm_qkv_rope(
    const bf16* __restrict__ X, const bf16* __restrict__ W3,
    const int* __restrict__ pos_ids, const float2* __restrict__ tab,
    bf16* __restrict__ Qo, bf16* __restrict__ Ko, bf16* __restrict__ Vt) {
  __shared__ __align__(16) bf16 As[128 * 64];
  __shared__ __align__(16) bf16 Bs[128 * 64];
  const int tid = threadIdx.x;
  const int wave = tid >> 6, lane = tid & 63;
  const int c15 = lane & 15, g = lane >> 4;
  const int sw7 = c15 & 7;
  const int mw = (wave & 1) * 64, nw = (wave >> 1) * 64;
  const int row0 = blockIdx.x * 128;
  const int n0 = blockIdx.y * 128;
  const bf16* Asrc = X + (size_t)row0 * DM;
  const bf16* Bsrc = W3 + (size_t)n0 * DM;

  // staging: granule id = j*256 + tid over 128 rows x 8 slots; dest elem = id*8 (linear).
  // source col granule = slot ^ (row&7)  (swizzle on the global side).
#define QKV_STAGE(kt_)                                                         \
  _Pragma("unroll") for (int j = 0; j < 4; ++j) {                              \
    const int id = j * 256 + tid;                                              \
    const int rr = id >> 3, cp = id & 7;                                       \
    const int cs = cp ^ (rr & 7);                                              \
    gl_lds16(Asrc + (size_t)rr * DM + (kt_)*64 + cs * 8,                       \
             &As[(size_t)(j * 2048 + wave * 512) + (size_t)(lane * 8)]);       \
    gl_lds16(Bsrc + (size_t)rr * DM + (kt_)*64 + cs * 8,                       \
             &Bs[(size_t)(j * 2048 + wave * 512) + (size_t)(lane * 8)]);       \
  }

  f32x4 acc[4][4] = {};
  for (int kt = 0; kt < DM / 64; ++kt) {
    __syncthreads();  // WAR: previous compute done reading the buffer
    QKV_STAGE(kt)
    __syncthreads();  // RAW: tile resident (barrier drains vmcnt)
#pragma unroll
    for (int h = 0; h < 2; ++h) {
      bf16x8 af[4], bfr[4];
#pragma unroll
      for (int t = 0; t < 4; ++t) {
        const int slot = ((h << 2) | g) ^ sw7;
        af[t] = *(const bf16x8*)&As[(mw + t * 16 + c15) * 64 + slot * 8];
        bfr[t] = *(const bf16x8*)&Bs[(nw + t * 16 + c15) * 64 + slot * 8];
      }
#pragma unroll
      for (int mt = 0; mt < 4; ++mt)
#pragma unroll
        for (int nt = 0; nt < 4; ++nt)
          acc[mt][nt] = MFMA16(af[mt], bfr[nt], acc[mt][nt]);
    }
  }
#undef QKV_STAGE

  // epilogue: C/D col = nt*16+c15, row = g*4+r
  const int Wsel = n0 >> 10;             // 0=q, 1=k, 2=v
  const int colbase = (n0 & 1023) + nw;  // multiple of 64 -> one head
  const int h = colbase >> 6;
  if (Wsel == 2) {
#pragma unroll
    for (int mt = 0; mt < 4; ++mt) {
      const int srow = row0 + mw + mt * 16 + g * 4;
      const int bb = srow >> 11, ss = srow & 2047;
      // interleave key order within each 32-block so flash's PV B-frag key order
      // (keys {4g..4g+3, 16+4g..16+4g+3} per granule) is one contiguous b128:
      // p = (k&~31) | ((k&12)<<1) | ((k&16)>>2) | (k&3); ss is a multiple of 4.
      const int ssp = (ss & ~31) | ((ss & 12) << 1) | ((ss & 16) >> 2);
      const size_t vb = ((size_t)(bb * H_N + h) * DK) * S_N + ssp;
#pragma unroll
      for (int nt = 0; nt < 4; ++nt) {
        bf16x4 v4;
#pragma unroll
        for (int r = 0; r < 4; ++r) v4[r] = (bf16)acc[mt][nt][r];
        *(bf16x4*)&Vt[vb + (size_t)(nt * 16 + c15) * S_N] = v4;
      }
    }
  } else {
    bf16* dst = (Wsel == 0) ? Qo : Ko;
    // Q pre-scale folds 1/sqrt(64) AND log2(e) so flash can use exp2 directly.
    const float sc = (Wsel == 0) ? 0.125f * 1.44269504088896f : 1.0f;
#pragma unroll
    for (int mt = 0; mt < 4; ++mt) {
#pragma unroll
      for (int r = 0; r < 4; ++r) {
        const int row = row0 + mw + mt * 16 + g * 4 + r;
        const int bb = row >> 11, ss = row & 2047;
        const int pos = pos_ids[row];
        const float2 c0 = tab[pos * 32 + c15];       // freq j = c15
        const float2 c1 = tab[pos * 32 + 16 + c15];  // freq j = 16+c15
        const size_t base = ((size_t)(bb * H_N + h) * S_N + ss) * DK;
#pragma unroll
        for (int ntp = 0; ntp < 2; ++ntp) {
          float x1 = acc[mt][ntp][r], x2 = acc[mt][ntp + 2][r];
          float cs = ntp ? c1.x : c0.x, sn = ntp ? c1.y : c0.y;
          dst[base + ntp * 16 + c15] = (bf16)((x1 * cs - x2 * sn) * sc);
          dst[base + ntp * 16 + c15 + 32] = (bf16)((x2 * cs + x1 * sn) * sc);
        }
      }
    }
  }
}

// ---------------- flash attention: 8 waves = (qh: 4 x 32-q) x (ky: 2 x 32-key slice) ----------------
// R14 structure. R20: PV via K=32 MFMA with B-frag = CONCATENATED exp2 registers.
// The MFMA k-slot -> actual-key mapping is ours to choose (we already permute V's key
// order at the producer): define slot (g,j): j<4 -> key 4g+j, j>=4 -> key 16+4g+(j-4).
// That is exactly [A.h4 | Bp.h4] in registers, and exactly the key order V's b128
// granule already has. 8x K16 MFMA -> 4x K32 MFMA: PV pipe time HALVES (20.8 -> 13.9us
// MFMA-busy), zero data movement, zero producer changes.
__global__ __launch_bounds__(512, 2) void flash_attn(
    const bf16* __restrict__ Q, const bf16* __restrict__ K,
    const bf16* __restrict__ Vt, bf16* __restrict__ ctx) {
  // staging: K[ky][buf] at (ky*2+buf)*2048, V at 8192+...; merge redbuf aliases smem
  // (needs 4 qh x 32 rows x 68 floats = 34816 B = 17408 elements -> smem sized for merge).
  __shared__ __align__(16) bf16 smem[17408];
  __shared__ float lred[4][2][16];
  float* redbuf = (float*)smem;

  const int tid = threadIdx.x;
  const int wave = tid >> 6, lane = tid & 63;
  const int c15 = lane & 15, g = lane >> 4;
  const int qh = wave >> 1, ky = wave & 1;  // qh 0..3 (32-q slice), ky 0..1 (32-key slice)
  const int bh = blockIdx.x & 31;   // b*16+h (XCD = bh%8)
  const int qt = blockIdx.x >> 5;   // 128-query tile, 0..15
  const size_t hb = (size_t)bh * S_N * DK;
  const bf16* Qb = Q + hb;
  const bf16* Kb = K + hb;
  const bf16* Vb = Vt + hb;  // [d][s] rows, stride S_N (keys interleaved per 32)

  // Q B-frags: 2 q-tiles of 16 for this wave's 32-query slice
  const int qb = qt * 128 + qh * 32;
  bf16x8 qf[2][2];
#pragma unroll
  for (int t = 0; t < 2; ++t) {
    qf[t][0] = *(const bf16x8*)&Qb[(size_t)(qb + t * 16 + c15) * DK + g * 8];
    qf[t][1] = *(const bf16x8*)&Qb[(size_t)(qb + t * 16 + c15) * DK + 32 + g * 8];
  }

  f32x4 O[2][4] = {};  // [q-tile][d-tile]: O^T row d = nt*16+g*4+r, col q = c15
  float l[2] = {0.f, 0.f};
  const int sw = c15 & 7;
  const int vslot = (g + (c15 >> 1)) & 3;  // V read-granule swizzle

  constexpr int NTK = S_N / 64;  // 32 iters; each wave sees its ky 32-key slice
#define STAGE(kt_, b_)                                                            \
  if (qh == 0) { /* stage K slice ky */                                           \
    const bf16* Ksrc = Kb + (size_t)((kt_)*64 + ky * 32) * DK;                    \
    _Pragma("unroll") for (int c = 0; c < 4; ++c) {                               \
      const int gi = c * 64 + lane;                                               \
      const int rr = gi >> 3, cp = gi & 7;                                        \
      const int cd = cp ^ (rr & 7);                                               \
      gl_lds16(Ksrc + (size_t)rr * 64 + cd * 8, &smem[(ky * 2 + (b_)) * 2048 + c * 512]); \
    }                                                                             \
  } else if (qh == 1) { /* stage V slice ky */                                    \
    const bf16* Vsrc = Vb + (kt_)*64 + ky * 32;                                   \
    _Pragma("unroll") for (int c = 0; c < 4; ++c) {                               \
      const int gi = c * 64 + lane;                                               \
      const int rv = gi >> 2, cpv = gi & 3;                                       \
      const int cdv = (cpv - ((rv & 15) >> 1)) & 3;                               \
      gl_lds16(Vsrc + (size_t)rv * S_N + cdv * 8, &smem[8192 + (ky * 2 + (b_)) * 2048 + c * 512]); \
    }                                                                             \
  }

  STAGE(0, 0)
  for (int kt = 0; kt < NTK; ++kt) {
    __syncthreads();  // tile kt resident (its loads were issued one full phase ago)
    if (kt + 1 < NTK) STAGE(kt + 1, (kt + 1) & 1)
    const bf16* Kl = &smem[(ky * 2 + (kt & 1)) * 2048];
    const bf16* Vl = &smem[8192 + (ky * 2 + (kt & 1)) * 2048];

    // K A-frags: 2 key-subtiles x 2 d-halves (granule-XOR swizzle, round-trips cd)
    bf16x8 kf[2][2];
#pragma unroll
    for (int nt = 0; nt < 2; ++nt) {
      const int krow = (nt * 16 + c15) * 64;
      kf[nt][0] = *(const bf16x8*)&Kl[krow + ((g ^ sw) * 8)];
      kf[nt][1] = *(const bf16x8*)&Kl[krow + (((4 | g) ^ sw) * 8)];
    }
    // V A-frags: 4 d-subtiles; granule g holds keys {4g..4g+3, 16+4g..16+4g+3}
    // (producer-side interleave) = exactly the K=32 k-slot order of the concat B-frag.
    bf16x8 vf[4];
#pragma unroll
    for (int nt = 0; nt < 4; ++nt)
      vf[nt] = *(const bf16x8*)&Vl[(nt * 16 + c15) * 32 + vslot * 8];

    // per q-tile: S^T = K·Q^T (32 keys x 16 q) -> exp2 -> PV via K=32 MFMA, B = concat regs
#pragma unroll
    for (int t = 0; t < 2; ++t) {
      f32x4 s0 = {}, s1 = {};
      s0 = MFMA16(kf[0][0], qf[t][0], s0);
      s0 = MFMA16(kf[0][1], qf[t][1], s0);
      s1 = MFMA16(kf[1][0], qf[t][0], s1);
      s1 = MFMA16(kf[1][1], qf[t][1], s1);
      union PF { bf16 h[8]; bf16x8 v; } Pk;
      float p0 = EXP2F(s0[0]), p1 = EXP2F(s0[1]), p2 = EXP2F(s0[2]), p3 = EXP2F(s0[3]);
      float p4 = EXP2F(s1[0]), p5 = EXP2F(s1[1]), p6 = EXP2F(s1[2]), p7 = EXP2F(s1[3]);
      l[t] += ((p0 + p1) + (p2 + p3)) + ((p4 + p5) + (p6 + p7));
      Pk.h[0] = (bf16)p0; Pk.h[1] = (bf16)p1; Pk.h[2] = (bf16)p2; Pk.h[3] = (bf16)p3;
      Pk.h[4] = (bf16)p4; Pk.h[5] = (bf16)p5; Pk.h[6] = (bf16)p6; Pk.h[7] = (bf16)p7;
      // Pk = P at k-slots g*8+j: j<4 -> key 4g+j (s0 rows), j>=4 -> key 16+4g+(j-4) (s1).
      // vf[nt] holds V at the SAME k-slot->key mapping -> direct K=32 contraction.
#pragma unroll
      for (int nt = 0; nt < 4; ++nt) O[t][nt] = MFMA16(vf[nt], Pk.v, O[t][nt]);
    }
  }
#undef STAGE

  // own-wave l reduction (sum over g-lanes sharing c15)
#pragma unroll
  for (int t = 0; t < 2; ++t) {
    l[t] += __shfl_xor(l[t], 16);
    l[t] += __shfl_xor(l[t], 32);
  }

  // cross-wave merge: ky=1 publishes O,l; ky=0 combines, normalizes, stores.
  __syncthreads();  // all waves done reading staging LDS (redbuf aliases it)
  if (ky == 1) {
#pragma unroll
    for (int t = 0; t < 2; ++t) {
#pragma unroll
      for (int nt = 0; nt < 4; ++nt)
        *(f32x4*)&redbuf[(qh * 32 + t * 16 + c15) * 68 + nt * 16 + g * 4] = O[t][nt];
      if (g == 0) lred[qh][t][c15] = l[t];
    }
  }
  __syncthreads();
  if (ky == 0) {
    const int bb = bh >> 4, hh = bh & 15;
#pragma unroll
    for (int t = 0; t < 2; ++t) {
      const float inv = 1.0f / (l[t] + lred[qh][t][c15]);
      const size_t base = ((size_t)(bb * S_N + qb + t * 16 + c15) * H_N + hh) * DK;
#pragma unroll
      for (int nt = 0; nt < 4; ++nt) {
        f32x4 o = *(const f32x4*)&redbuf[(qh * 32 + t * 16 + c15) * 68 + nt * 16 + g * 4];
        bf16x4 v4;
#pragma unroll
        for (int r = 0; r < 4; ++r) v4[r] = (bf16)((O[t][nt][r] + o[r]) * inv);
        *(bf16x4*)&ctx[base + nt * 16 + g * 4] = v4;
      }
    }
  }
}

// ---------------- output projection: out = ctx @ Wo^T (fp32), 64x128 tiles ----------------
// R18 structure: BK=64 single-buffer + 8-slot granule-XOR swizzle.
__global__ __launch_bounds__(256) void gemm_out(
    const bf16* __restrict__ Cx, const bf16* __restrict__ Wo,
    float* __restrict__ out) {
  __shared__ __align__(16) bf16 As[64 * 64];
  __shared__ __align__(16) bf16 Bs[128 * 64];
  const int tid = threadIdx.x;
  const int wave = tid >> 6, lane = tid & 63;
  const int c15 = lane & 15, g = lane >> 4;
  const int sw7 = c15 & 7;
  const int mw = (wave & 1) * 32, nw = (wave >> 1) * 64;
  const int row0 = blockIdx.x * 64;
  const int n0 = blockIdx.y * 128;
  const bf16* Asrc = Cx + (size_t)row0 * DM;
  const bf16* Bsrc = Wo + (size_t)n0 * DM;

#define OUT_STAGE(kt_)                                                         \
  _Pragma("unroll") for (int j = 0; j < 2; ++j) {                              \
    const int id = j * 256 + tid;                                              \
    const int rr = id >> 3, cp = id & 7;                                       \
    gl_lds16(Asrc + (size_t)rr * DM + (kt_)*64 + (cp ^ (rr & 7)) * 8,          \
             &As[(size_t)(j * 2048 + wave * 512) + (size_t)(lane * 8)]);       \
  }                                                                            \
  _Pragma("unroll") for (int j = 0; j < 4; ++j) {                              \
    const int id = j * 256 + tid;                                              \
    const int rr = id >> 3, cp = id & 7;                                       \
    gl_lds16(Bsrc + (size_t)rr * DM + (kt_)*64 + (cp ^ (rr & 7)) * 8,          \
             &Bs[(size_t)(j * 2048 + wave * 512) + (size_t)(lane * 8)]);       \
  }

  f32x4 acc[2][4] = {};
  for (int kt = 0; kt < DM / 64; ++kt) {
    __syncthreads();  // WAR
    OUT_STAGE(kt)
    __syncthreads();  // RAW
#pragma unroll
    for (int h = 0; h < 2; ++h) {
      const int slot = ((h << 2) | g) ^ sw7;
      bf16x8 af[2], bfr[4];
#pragma unroll
      for (int t = 0; t < 2; ++t)
        af[t] = *(const bf16x8*)&As[(mw + t * 16 + c15) * 64 + slot * 8];
#pragma unroll
      for (int t = 0; t < 4; ++t)
        bfr[t] = *(const bf16x8*)&Bs[(nw + t * 16 + c15) * 64 + slot * 8];
#pragma unroll
      for (int mt = 0; mt < 2; ++mt)
#pragma unroll
        for (int nt = 0; nt < 4; ++nt)
          acc[mt][nt] = MFMA16(af[mt], bfr[nt], acc[mt][nt]);
    }
  }
#undef OUT_STAGE
#pragma unroll
  for (int mt = 0; mt < 2; ++mt)
#pragma unroll
    for (int r = 0; r < 4; ++r) {
      const int row = row0 + mw + mt * 16 + g * 4 + r;
#pragma unroll
      for (int nt = 0; nt < 4; ++nt)
        out[(size_t)row * DM + n0 + nw + nt * 16 + c15] = acc[mt][nt][r];
    }
}

extern "C" void kernel_launch(void* const* d_in, const int* in_sizes, int n_in,
                              void* d_out, int out_size, void* d_ws, size_t ws_size,
                              hipStream_t stream) {
  const float* hs = (const float*)d_in[0];
  const int* pos = (const int*)d_in[1];
  const float* wq = (const float*)d_in[2];
  const float* wk = (const float*)d_in[3];
  const float* wv = (const float*)d_in[4];
  const float* wo = (const float*)d_in[5];
  float* out = (float*)d_out;
  bf16* ws = (bf16*)d_ws;
  float2* tab = (float2*)(ws + OFF_C);  // aliases ctx region; disjoint lifetime

  cast_all<<<8192, 256, 0, stream>>>(hs, wq, wk, wv, wo, ws, tab);

  dim3 gq(M_N / 128, (3 * DM) / 128);
  gemm_qkv_rope<<<gq, 256, 0, stream>>>(ws + OFF_X, ws + OFF_W, pos, tab,
                                        ws + OFF_Q, ws + OFF_K, ws + OFF_V);

  // grid 512: blockIdx = qt*32 + bh (128-query tiles, XCD-local per head); 512 threads = 8 waves
  flash_attn<<<B_N * H_N * (S_N / 128), 512, 0, stream>>>(
      ws + OFF_Q, ws + OFF_K, ws + OFF_V, ws + OFF_C);

  dim3 go(M_N / 64, DM / 128);
  gemm_out<<<go, 256, 0, stream>>>(ws + OFF_C, ws + OFF_W + 3 * NW, out);
}